// Round 4
// baseline (614.136 us; speedup 1.0000x reference)
//
#include <hip/hip_runtime.h>
#include <cstdint>

// Problem: M=16384, K=2048, N=2048 fp8(e4m3) delayed-scaling dense fwd.
#define M_DIM 16384
#define K_DIM 2048
#define N_DIM 2048

typedef float f32x4 __attribute__((ext_vector_type(4)));
typedef int   i32x8 __attribute__((ext_vector_type(8)));

// ---------------------------------------------------------------------------
// Kernel 1 (FUSED): quantize x [M,K] -> fp8 (blocks 0..4095) and
// quantize+transpose w [K,N] -> wq [N,K] fp8 (blocks 4096..5119).
// Verified round-3; unchanged this round (controlled experiment on gemm).
// ---------------------------------------------------------------------------
__global__ __launch_bounds__(256) void quant_fused_kernel(
    const float4* __restrict__ x, uint4* __restrict__ xq,
    const float* __restrict__ w, uint8_t* __restrict__ wq,
    const float* __restrict__ scale, unsigned int* __restrict__ amax)
{
    __shared__ float tile[64][68];
    __shared__ float red[4];
    const int bid = blockIdx.x;
    const int t = threadIdx.x;
    float m = 0.0f;

    if (bid < 4096) {
        // ---- x path: grid-stride float4, fused amax ----
        const int gid = bid * 256 + t;                // 0 .. 1048575
        const float s = scale[0];
#pragma unroll
        for (int j = 0; j < 8; ++j) {
            float4 v = x[gid + j * 1048576];
            m = fmaxf(m, fmaxf(fmaxf(fabsf(v.x), fabsf(v.y)),
                               fmaxf(fabsf(v.z), fabsf(v.w))));
            unsigned int p0 = __builtin_amdgcn_cvt_pk_fp8_f32(v.x * s, v.y * s, 0, false);
            unsigned int p  = __builtin_amdgcn_cvt_pk_fp8_f32(v.z * s, v.w * s, p0, true);
            ((unsigned int*)xq)[gid + j * 1048576] = p;   // 4 fp8/dword, coalesced
        }
    } else {
        // ---- w path: 64x64 LDS transpose tile, fused amax ----
        const int b2 = bid - 4096;                    // 0..1023
        const int nb = (b2 & 31) << 6;
        const int kb = (b2 >> 5) << 6;
        const float s = scale[1];
#pragma unroll
        for (int j = 0; j < 4; ++j) {
            int f = j * 256 + t;
            int row = f >> 4;
            int c4 = f & 15;
            float4 v = *(const float4*)(w + (size_t)(kb + row) * N_DIM + nb + c4 * 4);
            m = fmaxf(m, fmaxf(fmaxf(fabsf(v.x), fabsf(v.y)),
                               fmaxf(fabsf(v.z), fabsf(v.w))));
            *(float4*)(&tile[row][c4 * 4]) = v;
        }
        __syncthreads();
        const int n = t >> 2, c = t & 3;
        unsigned int pk[4];
#pragma unroll
        for (int jj = 0; jj < 4; ++jj) {
            float f0 = tile[c * 16 + jj * 4 + 0][n] * s;
            float f1 = tile[c * 16 + jj * 4 + 1][n] * s;
            float f2 = tile[c * 16 + jj * 4 + 2][n] * s;
            float f3 = tile[c * 16 + jj * 4 + 3][n] * s;
            unsigned int p = __builtin_amdgcn_cvt_pk_fp8_f32(f0, f1, 0, false);
            pk[jj] = __builtin_amdgcn_cvt_pk_fp8_f32(f2, f3, p, true);
        }
        *(uint4*)(wq + (size_t)(nb + n) * K_DIM + kb + c * 16) =
            make_uint4(pk[0], pk[1], pk[2], pk[3]);
    }

    // ---- common block reduction + device atomic (amax[0]=x, amax[1]=w) ----
#pragma unroll
    for (int off = 32; off > 0; off >>= 1)
        m = fmaxf(m, __shfl_down(m, off, 64));
    if ((t & 63) == 0) red[t >> 6] = m;
    __syncthreads();
    if (t == 0) {
        m = fmaxf(fmaxf(red[0], red[1]), fmaxf(red[2], red[3]));
        atomicMax(amax + (bid < 4096 ? 0 : 1), __float_as_uint(m));
    }
}

// ---------------------------------------------------------------------------
// Kernel 2: MX-scaled fp8 GEMM.  C[m,n] = sum_k Aq[m,k]*Bq[n,k].
// Round-0 verified structure. THIS ROUND'S ONLY CHANGE: LDS 33280 -> 32768 B.
// Theory: 33280 B (512 over the 32K boundary) rounds to a coarse allocation
// granule -> 2 blocks/CU (Occupancy 27%), and this kernel hides its per-K-step
// vmcnt(0) staging drain purely via cross-block TLP. <=32KB should give
// 4-5 blocks/CU. __launch_bounds__(256,5) requests it (VGPR 80 <= 102 cap).
//
// Layout change (bank-identical to the verified 2080-stride pad layout):
// group stride 2048, no pad; 16B granule n stored at physical granule
// p = n ^ ((n>>6)&1)  (involution, flips lo/hi granule for lanes >= 32).
//  * staging dst stays lane-linear contiguous: g*2048 + hh*1024 + lane*16;
//    owner-lane fl = hh*32+(lane>>1) unchanged; k-half selector (lane&1)^hh.
//  * reads: lanes<32 lo@32l hi@32l+16 (as before); lanes>=32 lo@32l+16 hi@32l.
//    Per-instruction banks: dwords 8l / 8l+4 -> same 8-phase pattern as r0.
// ---------------------------------------------------------------------------
#define GSTRIDE 2048
__global__ __launch_bounds__(256, 5) void gemm_fp8_kernel(
    const uint8_t* __restrict__ Aq, const uint8_t* __restrict__ Bq,
    const float* __restrict__ scale, const unsigned int* __restrict__ amax_bits,
    float* __restrict__ C)
{
    __shared__ uint8_t lA[8 * GSTRIDE];
    __shared__ uint8_t lB[8 * GSTRIDE];
    const int tid  = threadIdx.x;
    const int wave = tid >> 6;
    const int lane = tid & 63;
    const int wm = wave >> 1, wn = wave & 1;   // 2x2 wave grid, 64x64 per wave
    const int q = lane >> 4, r = lane & 15;

    const int bn = blockIdx.x;                 // 0..15
    const int bm = blockIdx.y;                 // 0..127
    const size_t a_base = (size_t)bm * 128 * K_DIM;
    const size_t b_base = (size_t)bn * 128 * K_DIM;

    // Staging geometry: wave handles segments s = j*4 + wave, s = 2g + hh.
    int srow[4], skoff[4], sdst[4];
#pragma unroll
    for (int j = 0; j < 4; ++j) {
        const int s  = j * 4 + wave;
        const int g  = s >> 1, hh = s & 1;
        const int fl = hh * 32 + (lane >> 1);              // owner lane
        srow[j]  = g * 16 + (fl & 15);
        skoff[j] = (fl >> 4) * 32 + ((lane & 1) ^ hh) * 16; // XOR'd k-half
        sdst[j]  = g * GSTRIDE + hh * 1024 + lane * 16;     // lane-linear
    }
    // Fragment read offsets (granule-XOR layout)
    const int lo_off = (((lane << 1)    ) ^ (lane >> 5)) << 4;
    const int hi_off = (((lane << 1) | 1) ^ (lane >> 5)) << 4;

    f32x4 acc[4][4];
#pragma unroll
    for (int i = 0; i < 4; ++i)
#pragma unroll
        for (int j = 0; j < 4; ++j) acc[i][j] = (f32x4){0.f, 0.f, 0.f, 0.f};

    const int SONE = 0x7F7F7F7F;   // e8m0 scale = 1.0 in every byte

    for (int kt = 0; kt < K_DIM / 128; ++kt) {
        __syncthreads();
        const size_t kg = (size_t)kt * 128;
#pragma unroll
        for (int j = 0; j < 4; ++j) {
            const uint8_t* ga = Aq + a_base + (size_t)srow[j] * K_DIM + kg + skoff[j];
            const uint8_t* gb = Bq + b_base + (size_t)srow[j] * K_DIM + kg + skoff[j];
            __builtin_amdgcn_global_load_lds(
                (const __attribute__((address_space(1))) uint32_t*)ga,
                (__attribute__((address_space(3))) uint32_t*)(lA + sdst[j]), 16, 0, 0);
            __builtin_amdgcn_global_load_lds(
                (const __attribute__((address_space(1))) uint32_t*)gb,
                (__attribute__((address_space(3))) uint32_t*)(lB + sdst[j]), 16, 0, 0);
        }
        __syncthreads();

        i32x8 a_frag[4], b_frag[4];
#pragma unroll
        for (int mi = 0; mi < 4; ++mi) {
            const uint8_t* pa = lA + (wm * 4 + mi) * GSTRIDE;
            int4 lo = *(const int4*)(pa + lo_off);
            int4 hi = *(const int4*)(pa + hi_off);
            a_frag[mi] = (i32x8){lo.x, lo.y, lo.z, lo.w, hi.x, hi.y, hi.z, hi.w};
        }
#pragma unroll
        for (int ni = 0; ni < 4; ++ni) {
            const uint8_t* pb = lB + (wn * 4 + ni) * GSTRIDE;
            int4 lo = *(const int4*)(pb + lo_off);
            int4 hi = *(const int4*)(pb + hi_off);
            b_frag[ni] = (i32x8){lo.x, lo.y, lo.z, lo.w, hi.x, hi.y, hi.z, hi.w};
        }
#pragma unroll
        for (int mi = 0; mi < 4; ++mi)
#pragma unroll
            for (int ni = 0; ni < 4; ++ni)
                acc[mi][ni] = __builtin_amdgcn_mfma_scale_f32_16x16x128_f8f6f4(
                    a_frag[mi], b_frag[ni], acc[mi][ni],
                    0 /*cbsz: fp8*/, 0 /*blgp: fp8*/,
                    0, SONE, 0, SONE);
    }

    // epilogue: D col = lane&15, row = q*4 + reg (m89-verified, shape-determined)
    const float sinv = (1.0f / scale[0]) * (1.0f / scale[1]);
#pragma unroll
    for (int mi = 0; mi < 4; ++mi) {
#pragma unroll
        for (int ni = 0; ni < 4; ++ni) {
            const int col  = bn * 128 + wn * 64 + ni * 16 + r;
            const int row0 = bm * 128 + wm * 64 + mi * 16 + q * 4;
#pragma unroll
            for (int rr = 0; rr < 4; ++rr)
                C[(size_t)(row0 + rr) * N_DIM + col] = acc[mi][ni][rr] * sinv;
        }
    }

    // ---- finalize tail: block (0,0), lanes 0-1 ----
    // Faithful _sf_compute incl. tf.where ordering; rolled 1-row history = 0.
    if (blockIdx.x == 0 && blockIdx.y == 0 && tid < 2) {
        float* out_tail = C + (size_t)M_DIM * N_DIM;
        const float amax = __uint_as_float(amax_bits[tid]);
        const float sc = scale[tid];
        const float e = floorf(log2f(448.0f / amax));
        float sf = roundf(exp2f(fabsf(e)));
        sf = (amax > 0.0f) ? sf : sc;
        sf = isinf(amax) ? sf : sc;      // faithful: finite amax collapses to scale
        if (e < 0.0f) sf = 1.0f / sf;
        out_tail[tid] = sf;              // new_scale
        out_tail[2 + tid] = 0.0f;        // rolled history (single row -> zeros)
    }
}

// ---------------------------------------------------------------------------
extern "C" void kernel_launch(void* const* d_in, const int* in_sizes, int n_in,
                              void* d_out, int out_size, void* d_ws, size_t ws_size,
                              hipStream_t stream)
{
    const float* x     = (const float*)d_in[0];
    const float* w     = (const float*)d_in[1];
    const float* scale = (const float*)d_in[2];

    uint8_t* ws = (uint8_t*)d_ws;
    uint8_t* xq = ws;                                            // M*K fp8 (32 MB)
    uint8_t* wq = ws + (size_t)M_DIM * K_DIM;                    // N*K fp8 (4 MB)
    unsigned int* amax = (unsigned int*)(ws + (size_t)M_DIM * K_DIM + (size_t)N_DIM * K_DIM);

    hipMemsetAsync(amax, 0, 2 * sizeof(unsigned int), stream);

    quant_fused_kernel<<<5120, 256, 0, stream>>>(
        (const float4*)x, (uint4*)xq, w, wq, scale, amax);

    dim3 gg(N_DIM / 128, M_DIM / 128);
    gemm_fp8_kernel<<<gg, 256, 0, stream>>>(xq, wq, scale, amax, (float*)d_out);
}

// Round 5
// 341.979 us; speedup vs baseline: 1.7958x; 1.7958x over previous
//
#include <hip/hip_runtime.h>
#include <cstdint>

// Problem: M=16384, K=2048, N=2048 fp8(e4m3) delayed-scaling dense fwd.
#define M_DIM 16384
#define K_DIM 2048
#define N_DIM 2048

typedef float f32x4 __attribute__((ext_vector_type(4)));
typedef int   i32x8 __attribute__((ext_vector_type(8)));

// ---------------------------------------------------------------------------
// Kernel 1 (FUSED): quantize x [M,K] -> fp8 (blocks 0..4095) and
// quantize+transpose w [K,N] -> wq [N,K] fp8 (blocks 4096..5119).
// Verified round-3; unchanged (controlled experiment on gemm).
// ---------------------------------------------------------------------------
__global__ __launch_bounds__(256) void quant_fused_kernel(
    const float4* __restrict__ x, uint4* __restrict__ xq,
    const float* __restrict__ w, uint8_t* __restrict__ wq,
    const float* __restrict__ scale, unsigned int* __restrict__ amax)
{
    __shared__ float tile[64][68];
    __shared__ float red[4];
    const int bid = blockIdx.x;
    const int t = threadIdx.x;
    float m = 0.0f;

    if (bid < 4096) {
        // ---- x path: grid-stride float4, fused amax ----
        const int gid = bid * 256 + t;                // 0 .. 1048575
        const float s = scale[0];
#pragma unroll
        for (int j = 0; j < 8; ++j) {
            float4 v = x[gid + j * 1048576];
            m = fmaxf(m, fmaxf(fmaxf(fabsf(v.x), fabsf(v.y)),
                               fmaxf(fabsf(v.z), fabsf(v.w))));
            unsigned int p0 = __builtin_amdgcn_cvt_pk_fp8_f32(v.x * s, v.y * s, 0, false);
            unsigned int p  = __builtin_amdgcn_cvt_pk_fp8_f32(v.z * s, v.w * s, p0, true);
            ((unsigned int*)xq)[gid + j * 1048576] = p;   // 4 fp8/dword, coalesced
        }
    } else {
        // ---- w path: 64x64 LDS transpose tile, fused amax ----
        const int b2 = bid - 4096;                    // 0..1023
        const int nb = (b2 & 31) << 6;
        const int kb = (b2 >> 5) << 6;
        const float s = scale[1];
#pragma unroll
        for (int j = 0; j < 4; ++j) {
            int f = j * 256 + t;
            int row = f >> 4;
            int c4 = f & 15;
            float4 v = *(const float4*)(w + (size_t)(kb + row) * N_DIM + nb + c4 * 4);
            m = fmaxf(m, fmaxf(fmaxf(fabsf(v.x), fabsf(v.y)),
                               fmaxf(fabsf(v.z), fabsf(v.w))));
            *(float4*)(&tile[row][c4 * 4]) = v;
        }
        __syncthreads();
        const int n = t >> 2, c = t & 3;
        unsigned int pk[4];
#pragma unroll
        for (int jj = 0; jj < 4; ++jj) {
            float f0 = tile[c * 16 + jj * 4 + 0][n] * s;
            float f1 = tile[c * 16 + jj * 4 + 1][n] * s;
            float f2 = tile[c * 16 + jj * 4 + 2][n] * s;
            float f3 = tile[c * 16 + jj * 4 + 3][n] * s;
            unsigned int p = __builtin_amdgcn_cvt_pk_fp8_f32(f0, f1, 0, false);
            pk[jj] = __builtin_amdgcn_cvt_pk_fp8_f32(f2, f3, p, true);
        }
        *(uint4*)(wq + (size_t)(nb + n) * K_DIM + kb + c * 16) =
            make_uint4(pk[0], pk[1], pk[2], pk[3]);
    }

    // ---- common block reduction + device atomic (amax[0]=x, amax[1]=w) ----
#pragma unroll
    for (int off = 32; off > 0; off >>= 1)
        m = fmaxf(m, __shfl_down(m, off, 64));
    if ((t & 63) == 0) red[t >> 6] = m;
    __syncthreads();
    if (t == 0) {
        m = fmaxf(fmaxf(red[0], red[1]), fmaxf(red[2], red[3]));
        atomicMax(amax + (bid < 4096 ? 0 : 1), __float_as_uint(m));
    }
}

// ---------------------------------------------------------------------------
// Kernel 2: MX-scaled fp8 GEMM.  C[m,n] = sum_k Aq[m,k]*Bq[n,k].
// Round-4 post-mortem: LDS 32768 confirmed the granularity theory
// (Occupancy 27->44%), but __launch_bounds__(256,5) capped VGPR at 48 <
// the ~80 the kernel needs (acc alone = 64) -> acc spilled to scratch
// (WRITE_SIZE 131->869MB, gemm 378us). THIS ROUND: keep the 32768-B
// granule-XOR layout (correctness proven in r4), drop the min-waves cap.
// Expect VGPR ~80 (128-granule -> 4 waves/SIMD) x LDS 5-blocks -> ~4
// blocks/CU resident, cross-block TLP hides the per-K-step staging drain.
//
// Layout (bank-identical to the verified 2080-pad layout): group stride
// 2048; 16B granule n at physical granule p = n ^ ((n>>6)&1).
//  * staging dst lane-linear contiguous: g*2048 + hh*1024 + lane*16;
//    owner-lane fl = hh*32+(lane>>1); k-half selector (lane&1)^hh.
//  * reads: lanes<32 lo@32l hi@32l+16; lanes>=32 swapped. Same 8-phase
//    bank pattern; SQ_LDS_BANK_CONFLICT 4/read is the wave64-b128 floor.
// ---------------------------------------------------------------------------
#define GSTRIDE 2048
__global__ __launch_bounds__(256) void gemm_fp8_kernel(
    const uint8_t* __restrict__ Aq, const uint8_t* __restrict__ Bq,
    const float* __restrict__ scale, const unsigned int* __restrict__ amax_bits,
    float* __restrict__ C)
{
    __shared__ uint8_t lA[8 * GSTRIDE];
    __shared__ uint8_t lB[8 * GSTRIDE];
    const int tid  = threadIdx.x;
    const int wave = tid >> 6;
    const int lane = tid & 63;
    const int wm = wave >> 1, wn = wave & 1;   // 2x2 wave grid, 64x64 per wave
    const int q = lane >> 4, r = lane & 15;

    const int bn = blockIdx.x;                 // 0..15
    const int bm = blockIdx.y;                 // 0..127
    const size_t a_base = (size_t)bm * 128 * K_DIM;
    const size_t b_base = (size_t)bn * 128 * K_DIM;

    // Staging geometry: wave handles segments s = j*4 + wave, s = 2g + hh.
    int srow[4], skoff[4], sdst[4];
#pragma unroll
    for (int j = 0; j < 4; ++j) {
        const int s  = j * 4 + wave;
        const int g  = s >> 1, hh = s & 1;
        const int fl = hh * 32 + (lane >> 1);              // owner lane
        srow[j]  = g * 16 + (fl & 15);
        skoff[j] = (fl >> 4) * 32 + ((lane & 1) ^ hh) * 16; // XOR'd k-half
        sdst[j]  = g * GSTRIDE + hh * 1024 + lane * 16;     // lane-linear
    }
    // Fragment read offsets (granule-XOR layout)
    const int lo_off = (((lane << 1)    ) ^ (lane >> 5)) << 4;
    const int hi_off = (((lane << 1) | 1) ^ (lane >> 5)) << 4;

    f32x4 acc[4][4];
#pragma unroll
    for (int i = 0; i < 4; ++i)
#pragma unroll
        for (int j = 0; j < 4; ++j) acc[i][j] = (f32x4){0.f, 0.f, 0.f, 0.f};

    const int SONE = 0x7F7F7F7F;   // e8m0 scale = 1.0 in every byte

    for (int kt = 0; kt < K_DIM / 128; ++kt) {
        __syncthreads();
        const size_t kg = (size_t)kt * 128;
#pragma unroll
        for (int j = 0; j < 4; ++j) {
            const uint8_t* ga = Aq + a_base + (size_t)srow[j] * K_DIM + kg + skoff[j];
            const uint8_t* gb = Bq + b_base + (size_t)srow[j] * K_DIM + kg + skoff[j];
            __builtin_amdgcn_global_load_lds(
                (const __attribute__((address_space(1))) uint32_t*)ga,
                (__attribute__((address_space(3))) uint32_t*)(lA + sdst[j]), 16, 0, 0);
            __builtin_amdgcn_global_load_lds(
                (const __attribute__((address_space(1))) uint32_t*)gb,
                (__attribute__((address_space(3))) uint32_t*)(lB + sdst[j]), 16, 0, 0);
        }
        __syncthreads();

        i32x8 a_frag[4], b_frag[4];
#pragma unroll
        for (int mi = 0; mi < 4; ++mi) {
            const uint8_t* pa = lA + (wm * 4 + mi) * GSTRIDE;
            int4 lo = *(const int4*)(pa + lo_off);
            int4 hi = *(const int4*)(pa + hi_off);
            a_frag[mi] = (i32x8){lo.x, lo.y, lo.z, lo.w, hi.x, hi.y, hi.z, hi.w};
        }
#pragma unroll
        for (int ni = 0; ni < 4; ++ni) {
            const uint8_t* pb = lB + (wn * 4 + ni) * GSTRIDE;
            int4 lo = *(const int4*)(pb + lo_off);
            int4 hi = *(const int4*)(pb + hi_off);
            b_frag[ni] = (i32x8){lo.x, lo.y, lo.z, lo.w, hi.x, hi.y, hi.z, hi.w};
        }
#pragma unroll
        for (int mi = 0; mi < 4; ++mi)
#pragma unroll
            for (int ni = 0; ni < 4; ++ni)
                acc[mi][ni] = __builtin_amdgcn_mfma_scale_f32_16x16x128_f8f6f4(
                    a_frag[mi], b_frag[ni], acc[mi][ni],
                    0 /*cbsz: fp8*/, 0 /*blgp: fp8*/,
                    0, SONE, 0, SONE);
    }

    // epilogue: D col = lane&15, row = q*4 + reg (m89-verified, shape-determined)
    const float sinv = (1.0f / scale[0]) * (1.0f / scale[1]);
#pragma unroll
    for (int mi = 0; mi < 4; ++mi) {
#pragma unroll
        for (int ni = 0; ni < 4; ++ni) {
            const int col  = bn * 128 + wn * 64 + ni * 16 + r;
            const int row0 = bm * 128 + wm * 64 + mi * 16 + q * 4;
#pragma unroll
            for (int rr = 0; rr < 4; ++rr)
                C[(size_t)(row0 + rr) * N_DIM + col] = acc[mi][ni][rr] * sinv;
        }
    }

    // ---- finalize tail: block (0,0), lanes 0-1 ----
    // Faithful _sf_compute incl. tf.where ordering; rolled 1-row history = 0.
    if (blockIdx.x == 0 && blockIdx.y == 0 && tid < 2) {
        float* out_tail = C + (size_t)M_DIM * N_DIM;
        const float amax = __uint_as_float(amax_bits[tid]);
        const float sc = scale[tid];
        const float e = floorf(log2f(448.0f / amax));
        float sf = roundf(exp2f(fabsf(e)));
        sf = (amax > 0.0f) ? sf : sc;
        sf = isinf(amax) ? sf : sc;      // faithful: finite amax collapses to scale
        if (e < 0.0f) sf = 1.0f / sf;
        out_tail[tid] = sf;              // new_scale
        out_tail[2 + tid] = 0.0f;        // rolled history (single row -> zeros)
    }
}

// ---------------------------------------------------------------------------
extern "C" void kernel_launch(void* const* d_in, const int* in_sizes, int n_in,
                              void* d_out, int out_size, void* d_ws, size_t ws_size,
                              hipStream_t stream)
{
    const float* x     = (const float*)d_in[0];
    const float* w     = (const float*)d_in[1];
    const float* scale = (const float*)d_in[2];

    uint8_t* ws = (uint8_t*)d_ws;
    uint8_t* xq = ws;                                            // M*K fp8 (32 MB)
    uint8_t* wq = ws + (size_t)M_DIM * K_DIM;                    // N*K fp8 (4 MB)
    unsigned int* amax = (unsigned int*)(ws + (size_t)M_DIM * K_DIM + (size_t)N_DIM * K_DIM);

    hipMemsetAsync(amax, 0, 2 * sizeof(unsigned int), stream);

    quant_fused_kernel<<<5120, 256, 0, stream>>>(
        (const float4*)x, (uint4*)xq, w, wq, scale, amax);

    dim3 gg(N_DIM / 128, M_DIM / 128);
    gemm_fp8_kernel<<<gg, 256, 0, stream>>>(xq, wq, scale, amax, (float*)d_out);
}

// Round 6
// 318.430 us; speedup vs baseline: 1.9286x; 1.0740x over previous
//
#include <hip/hip_runtime.h>
#include <cstdint>

// Problem: M=16384, K=2048, N=2048 fp8(e4m3) delayed-scaling dense fwd.
#define M_DIM 16384
#define K_DIM 2048
#define N_DIM 2048

typedef float f32x4 __attribute__((ext_vector_type(4)));
typedef int   i32x8 __attribute__((ext_vector_type(8)));

// ---------------------------------------------------------------------------
// Kernel 1 (FUSED): quantize x [M,K] -> fp8 (blocks 0..4095) and
// quantize+transpose w [K,N] -> wq [N,K] fp8 (blocks 4096..5119).
// Changes vs verified r3:
//  * amax protocol: per-block max -> partials[bid] (plain store, no init
//    needed) instead of atomicMax; removes the hipMemsetAsync dispatch.
//  * w-path tile reads were 4-way bank conflicts (68 = 4 mod 32; the four
//    row-groups c*16 collapse onto the same bank). Column rotation
//    pcol = (col + 8*(row>>4)) & 63 spreads the c-groups by 8 banks ->
//    2 lanes/bank (free, m136). Write side: uniform shift per wave (row>>4
//    is wave-uniform per j) -> bank pattern unchanged, float4-aligned.
// ---------------------------------------------------------------------------
__global__ __launch_bounds__(256) void quant_fused_kernel(
    const float4* __restrict__ x, uint4* __restrict__ xq,
    const float* __restrict__ w, uint8_t* __restrict__ wq,
    const float* __restrict__ scale, float* __restrict__ partials)
{
    __shared__ float tile[64][68];
    __shared__ float red[4];
    const int bid = blockIdx.x;
    const int t = threadIdx.x;
    float m = 0.0f;

    if (bid < 4096) {
        // ---- x path: grid-stride float4, fused amax ----
        const int gid = bid * 256 + t;                // 0 .. 1048575
        const float s = scale[0];
#pragma unroll
        for (int j = 0; j < 8; ++j) {
            float4 v = x[gid + j * 1048576];
            m = fmaxf(m, fmaxf(fmaxf(fabsf(v.x), fabsf(v.y)),
                               fmaxf(fabsf(v.z), fabsf(v.w))));
            unsigned int p0 = __builtin_amdgcn_cvt_pk_fp8_f32(v.x * s, v.y * s, 0, false);
            unsigned int p  = __builtin_amdgcn_cvt_pk_fp8_f32(v.z * s, v.w * s, p0, true);
            ((unsigned int*)xq)[gid + j * 1048576] = p;   // 4 fp8/dword, coalesced
        }
    } else {
        // ---- w path: 64x64 LDS transpose tile, fused amax ----
        const int b2 = bid - 4096;                    // 0..1023
        const int nb = (b2 & 31) << 6;
        const int kb = (b2 >> 5) << 6;
        const float s = scale[1];
#pragma unroll
        for (int j = 0; j < 4; ++j) {
            int f = j * 256 + t;
            int row = f >> 4;
            int c4 = f & 15;
            float4 v = *(const float4*)(w + (size_t)(kb + row) * N_DIM + nb + c4 * 4);
            m = fmaxf(m, fmaxf(fmaxf(fabsf(v.x), fabsf(v.y)),
                               fmaxf(fabsf(v.z), fabsf(v.w))));
            // column rotation: logical float col x -> (x + 8*(row>>4)) & 63
            const int pc = ((c4 << 2) + ((row >> 4) << 3)) & 63;
            *(float4*)(&tile[row][pc]) = v;
        }
        __syncthreads();
        const int n = t >> 2, c = t & 3;
        const int sh = c << 3;                        // rows c*16+k: row>>4 == c
        unsigned int pk[4];
#pragma unroll
        for (int jj = 0; jj < 4; ++jj) {
            float f0 = tile[c * 16 + jj * 4 + 0][(n + sh) & 63] * s;
            float f1 = tile[c * 16 + jj * 4 + 1][(n + sh) & 63] * s;
            float f2 = tile[c * 16 + jj * 4 + 2][(n + sh) & 63] * s;
            float f3 = tile[c * 16 + jj * 4 + 3][(n + sh) & 63] * s;
            unsigned int p = __builtin_amdgcn_cvt_pk_fp8_f32(f0, f1, 0, false);
            pk[jj] = __builtin_amdgcn_cvt_pk_fp8_f32(f2, f3, p, true);
        }
        *(uint4*)(wq + (size_t)(nb + n) * K_DIM + kb + c * 16) =
            make_uint4(pk[0], pk[1], pk[2], pk[3]);
    }

    // ---- per-block max -> partials[bid] (no atomic, no init required) ----
#pragma unroll
    for (int off = 32; off > 0; off >>= 1)
        m = fmaxf(m, __shfl_down(m, off, 64));
    if ((t & 63) == 0) red[t >> 6] = m;
    __syncthreads();
    if (t == 0) {
        m = fmaxf(fmaxf(red[0], red[1]), fmaxf(red[2], red[3]));
        partials[bid] = m;
    }
}

// ---------------------------------------------------------------------------
// Kernel 2: MX-scaled fp8 GEMM.  C[m,n] = sum_k Aq[m,k]*Bq[n,k].
// R3-VERBATIM core (93.6us, VGPR 80, 33280-B pad layout) — the empirical
// optimum of this structure after 3 failed restructures:
//   r1: 8-phase 256^2 -> prefetch distance < HBM latency, lost TLP (127us)
//   r2: merged phases -> scratch spills, WRITE 1.49GB (574us)
//   r5: 2048-XOR layout -> 2 LDS addr regs/frag, VGPR 100, occ 20.8% (104us)
// Remaining gap to the structure's LDS-BW floor (~60us) is drain overlap;
// cross-block TLP at 2 blocks/CU is what hides it, and every deepening
// attempt regressed. Tail: partials reduce + faithful _sf_compute.
//
// LDS layout (per matrix): 8 row-groups of 16 rows. Group g occupies
// [g*2080, g*2080+1024) = fragment half0 and [g*2080+1040, g*2080+2064) =
// half1, 16B pad between halves. Lane l's fragment: lo b128 at
// g*2080 + l*32 + (l>>5)*16, hi at +16 (offset:16 imm, one addr reg).
// 8-phase bank structure; 4 conflict-cyc/read is the wave64-b128 floor.
// ---------------------------------------------------------------------------
#define GSTRIDE 2080
__global__ __launch_bounds__(256) void gemm_fp8_kernel(
    const uint8_t* __restrict__ Aq, const uint8_t* __restrict__ Bq,
    const float* __restrict__ scale, const float* __restrict__ partials,
    float* __restrict__ C)
{
    __shared__ uint8_t lA[8 * GSTRIDE];
    __shared__ uint8_t lB[8 * GSTRIDE];
    const int tid  = threadIdx.x;
    const int wave = tid >> 6;
    const int lane = tid & 63;
    const int wm = wave >> 1, wn = wave & 1;   // 2x2 wave grid, 64x64 per wave
    const int q = lane >> 4, r = lane & 15;

    const int bn = blockIdx.x;                 // 0..15
    const int bm = blockIdx.y;                 // 0..127
    const size_t a_base = (size_t)bm * 128 * K_DIM;
    const size_t b_base = (size_t)bn * 128 * K_DIM;

    // Staging geometry: wave handles segments s = j*4 + wave, s = 2g + h.
    int srow[4], skoff[4], sdst[4];
#pragma unroll
    for (int j = 0; j < 4; ++j) {
        const int s  = j * 4 + wave;
        const int g  = s >> 1, hh = s & 1;
        const int fl = hh * 32 + (lane >> 1);
        srow[j]  = g * 16 + (fl & 15);
        skoff[j] = (fl >> 4) * 32 + (lane & 1) * 16;
        sdst[j]  = g * GSTRIDE + hh * 1040 + lane * 16;
    }
    // Fragment read base offset for this lane (within a group)
    const int frag_off = lane * 32 + (lane >> 5) * 16;

    f32x4 acc[4][4];
#pragma unroll
    for (int i = 0; i < 4; ++i)
#pragma unroll
        for (int j = 0; j < 4; ++j) acc[i][j] = (f32x4){0.f, 0.f, 0.f, 0.f};

    const int SONE = 0x7F7F7F7F;   // e8m0 scale = 1.0 in every byte

    for (int kt = 0; kt < K_DIM / 128; ++kt) {
        __syncthreads();
        const size_t kg = (size_t)kt * 128;
#pragma unroll
        for (int j = 0; j < 4; ++j) {
            const uint8_t* ga = Aq + a_base + (size_t)srow[j] * K_DIM + kg + skoff[j];
            const uint8_t* gb = Bq + b_base + (size_t)srow[j] * K_DIM + kg + skoff[j];
            __builtin_amdgcn_global_load_lds(
                (const __attribute__((address_space(1))) uint32_t*)ga,
                (__attribute__((address_space(3))) uint32_t*)(lA + sdst[j]), 16, 0, 0);
            __builtin_amdgcn_global_load_lds(
                (const __attribute__((address_space(1))) uint32_t*)gb,
                (__attribute__((address_space(3))) uint32_t*)(lB + sdst[j]), 16, 0, 0);
        }
        __syncthreads();

        i32x8 a_frag[4], b_frag[4];
#pragma unroll
        for (int mi = 0; mi < 4; ++mi) {
            const uint8_t* pa = lA + (wm * 4 + mi) * GSTRIDE + frag_off;
            int4 lo = *(const int4*)pa;
            int4 hi = *(const int4*)(pa + 16);
            a_frag[mi] = (i32x8){lo.x, lo.y, lo.z, lo.w, hi.x, hi.y, hi.z, hi.w};
        }
#pragma unroll
        for (int ni = 0; ni < 4; ++ni) {
            const uint8_t* pb = lB + (wn * 4 + ni) * GSTRIDE + frag_off;
            int4 lo = *(const int4*)pb;
            int4 hi = *(const int4*)(pb + 16);
            b_frag[ni] = (i32x8){lo.x, lo.y, lo.z, lo.w, hi.x, hi.y, hi.z, hi.w};
        }
#pragma unroll
        for (int mi = 0; mi < 4; ++mi)
#pragma unroll
            for (int ni = 0; ni < 4; ++ni)
                acc[mi][ni] = __builtin_amdgcn_mfma_scale_f32_16x16x128_f8f6f4(
                    a_frag[mi], b_frag[ni], acc[mi][ni],
                    0 /*cbsz: fp8*/, 0 /*blgp: fp8*/,
                    0, SONE, 0, SONE);
    }

    // epilogue: D col = lane&15, row = q*4 + reg (m89-verified, shape-determined)
    const float sinv = (1.0f / scale[0]) * (1.0f / scale[1]);
#pragma unroll
    for (int mi = 0; mi < 4; ++mi) {
#pragma unroll
        for (int ni = 0; ni < 4; ++ni) {
            const int col  = bn * 128 + wn * 64 + ni * 16 + r;
            const int row0 = bm * 128 + wm * 64 + mi * 16 + q * 4;
#pragma unroll
            for (int rr = 0; rr < 4; ++rr)
                C[(size_t)(row0 + rr) * N_DIM + col] = acc[mi][ni][rr] * sinv;
        }
    }

    // ---- tail: block (0,0) reduces partials (x: 0..4095, w: 4096..5119),
    // then faithful _sf_compute incl. tf.where ordering; rolled history = 0.
    // 20KB of loads by one block, hidden behind the other 2047 blocks.
    if (blockIdx.x == 0 && blockIdx.y == 0) {
        float mx = 0.0f, mw = 0.0f;
        for (int i = tid; i < 4096; i += 256) mx = fmaxf(mx, partials[i]);
        for (int i = tid; i < 1024; i += 256) mw = fmaxf(mw, partials[4096 + i]);
#pragma unroll
        for (int off = 32; off > 0; off >>= 1) {
            mx = fmaxf(mx, __shfl_down(mx, off, 64));
            mw = fmaxf(mw, __shfl_down(mw, off, 64));
        }
        __shared__ float rx[4], rw[4];
        if (lane == 0) { rx[wave] = mx; rw[wave] = mw; }
        __syncthreads();
        if (tid < 2) {
            float* out_tail = C + (size_t)M_DIM * N_DIM;
            const float amax = (tid == 0)
                ? fmaxf(fmaxf(rx[0], rx[1]), fmaxf(rx[2], rx[3]))
                : fmaxf(fmaxf(rw[0], rw[1]), fmaxf(rw[2], rw[3]));
            const float sc = scale[tid];
            const float e = floorf(log2f(448.0f / amax));
            float sf = roundf(exp2f(fabsf(e)));
            sf = (amax > 0.0f) ? sf : sc;
            sf = isinf(amax) ? sf : sc;  // faithful: finite amax collapses to scale
            if (e < 0.0f) sf = 1.0f / sf;
            out_tail[tid] = sf;          // new_scale
            out_tail[2 + tid] = 0.0f;    // rolled history (single row -> zeros)
        }
    }
}

// ---------------------------------------------------------------------------
extern "C" void kernel_launch(void* const* d_in, const int* in_sizes, int n_in,
                              void* d_out, int out_size, void* d_ws, size_t ws_size,
                              hipStream_t stream)
{
    const float* x     = (const float*)d_in[0];
    const float* w     = (const float*)d_in[1];
    const float* scale = (const float*)d_in[2];

    uint8_t* ws = (uint8_t*)d_ws;
    uint8_t* xq = ws;                                            // M*K fp8 (32 MB)
    uint8_t* wq = ws + (size_t)M_DIM * K_DIM;                    // N*K fp8 (4 MB)
    float* partials = (float*)(ws + (size_t)M_DIM * K_DIM + (size_t)N_DIM * K_DIM);

    quant_fused_kernel<<<5120, 256, 0, stream>>>(
        (const float4*)x, (uint4*)xq, w, wq, scale, partials);

    dim3 gg(N_DIM / 128, M_DIM / 128);
    gemm_fp8_kernel<<<gg, 256, 0, stream>>>(xq, wq, scale, partials, (float*)d_out);
}